// Round 1
// baseline (256.834 us; speedup 1.0000x reference)
//
#include <hip/hip_runtime.h>
#include <math.h>

// Problem constants (match reference)
#define B_    8192
#define F_    64
#define V_    1000
#define E_    64
#define T_    2
#define NTOK_ 16
#define G_    4
#define D_    256
#define K_    128   // T*E
#define LN_EPS 1e-5f

#define XSP   136   // xs row stride in bf16 elements (128 + 8 pad: even bank spread for b128 frag reads)

typedef __attribute__((ext_vector_type(8))) short  frag_ab;  // 8 bf16 = 4 VGPRs
typedef __attribute__((ext_vector_type(4))) float  frag_cd;  // 4 fp32 acc

static __device__ __forceinline__ unsigned short f2bf(float f) {
    // round-to-nearest-even fp32 -> bf16 (values are finite here)
    unsigned int u = __float_as_uint(f);
    u += 0x7FFFu + ((u >> 16) & 1u);
    return (unsigned short)(u >> 16);
}

// ---- prologue: W fp32 (D,K) -> bf16 in workspace (row-major, same layout) ----
__global__ __launch_bounds__(256) void convert_w_kernel(const float* __restrict__ W,
                                                        unsigned int* __restrict__ Wb_packed) {
    const int i = blockIdx.x * 256 + threadIdx.x;   // one uint = 2 bf16
    if (i < (D_ * K_) / 2) {
        const float2 v = *(const float2*)(W + (size_t)i * 2);
        Wb_packed[i] = (unsigned int)f2bf(v.x) | ((unsigned int)f2bf(v.y) << 16);
    }
}

// One block per batch row b. 256 threads = 4 waves.
// Phase 1: float4 gather + mean-pool -> xs[16][128] bf16 in LDS (indices read
//          directly from global: group_idx/int_feats/missing_mask are L1-hot).
// Phase 2: MFMA 16x16x32 bf16 with SWAPPED operands: A = W rows (M dim = output
//          col n), B = x (N dim = token). D layout: col(lane&15) = token,
//          row(4q+reg) = n-in-tile => each lane's accs all belong to ONE token.
//          LN stats: lane-local adds + shfl_xor(16),shfl_xor(32) + tiny LDS
//          cross-wave combine. Stores: float4 straight from registers.
// No hs staging buffer; 2 barriers total; LDS ~4.9 KB -> 8 blocks/CU.
__global__ __launch_bounds__(256) void fused_tokenizer_kernel(
    const int*   __restrict__ int_feats,     // (B, F)
    const int*   __restrict__ missing_mask,  // (B, F)
    const int*   __restrict__ group_idx,     // (NTOK, G)
    const float* __restrict__ emb_tables,    // (T, F, V, E)
    const float* __restrict__ missing_emb,   // (T, F, E)
    const unsigned short* __restrict__ Wb,   // (D, K) bf16
    const float* __restrict__ bias,          // (D,)
    const float* __restrict__ gamma,         // (D,)
    const float* __restrict__ beta,          // (D,)
    float*       __restrict__ out)           // (B, NTOK, D)
{
    __shared__ unsigned short xs[NTOK_][XSP];  // 4.3 KB, bf16 activations
    __shared__ float ps [NTOK_][4];            // per-wave partial sum   (token, wave)
    __shared__ float pss[NTOK_][4];            // per-wave partial sumsq

    const int tid  = threadIdx.x;
    const int b    = blockIdx.x;
    const int lane = tid & 63;
    const int wave = tid >> 6;

    const int* __restrict__ feats_row = int_feats    + b * F_;
    const int* __restrict__ mask_row  = missing_mask + b * F_;

    // ---- Phase 1: gather + mean-pool (float4 granularity) ----
    // chunk c in [0,512): n = c>>5 (token), r4 = c&31, t = r4>>4, e = (r4&15)*4
    // 16 consecutive lanes cover one 256B embedding row -> coalesced dwordx4.
#pragma unroll
    for (int i = 0; i < 2; ++i) {
        const int c  = i * 256 + tid;
        const int n  = c >> 5;
        const int r4 = c & 31;
        const int t  = r4 >> 4;
        const int e  = (r4 & 15) * 4;
        const int4 fv = *(const int4*)(group_idx + n * G_);   // 4 features of this token
        const int fs[4] = {fv.x, fv.y, fv.z, fv.w};
        float ax = 0.f, ay = 0.f, az = 0.f, aw = 0.f;
#pragma unroll
        for (int g = 0; g < G_; ++g) {
            const int f  = fs[g];
            const int id = feats_row[f];
            const float mk = (float)mask_row[f];              // branchless missing add
            const float4 v  = *(const float4*)(emb_tables + (((size_t)(t * F_ + f) * V_) + id) * E_ + e);
            const float4 mv = *(const float4*)(missing_emb + (size_t)(t * F_ + f) * E_ + e);
            ax += v.x + mk * mv.x;
            ay += v.y + mk * mv.y;
            az += v.z + mk * mv.z;
            aw += v.w + mk * mv.w;
        }
        union { unsigned int u[2]; } pk;
        pk.u[0] = (unsigned int)f2bf(0.25f * ax) | ((unsigned int)f2bf(0.25f * ay) << 16);
        pk.u[1] = (unsigned int)f2bf(0.25f * az) | ((unsigned int)f2bf(0.25f * aw) << 16);
        *(uint2*)(&xs[n][r4 * 4]) = make_uint2(pk.u[0], pk.u[1]);
    }
    __syncthreads();

    // ---- Phase 2: MFMA (swapped operands) + silu + LN, stores from registers ----
    {
        const int m = lane & 15;   // token index (D col)
        const int q = lane >> 4;   // quadrant

        // x fragment: lane holds x[token=m][k = 8q + j + 32s]
        frag_ab a[4];
#pragma unroll
        for (int s = 0; s < 4; ++s)
            a[s] = *(const frag_ab*)(&xs[m][32 * s + 8 * q]);

        float h[4][4];             // h[tt][reg]: silu outputs, cols 16*(4*wave+tt)+4q+reg, token m
        float s_acc = 0.f, ss_acc = 0.f;

#pragma unroll
        for (int tt = 0; tt < 4; ++tt) {
            const int nt   = wave * 4 + tt;        // n-tile
            const int nrow = nt * 16 + m;          // W row this lane supplies (A operand M dim)
            const unsigned short* wp = Wb + (size_t)nrow * K_ + 8 * q;

            frag_cd acc = {0.f, 0.f, 0.f, 0.f};
#pragma unroll
            for (int s = 0; s < 4; ++s) {
                const frag_ab wfr = *(const frag_ab*)(wp + 32 * s);
                // A = W (M = output col), B = x (N = token)
                acc = __builtin_amdgcn_mfma_f32_16x16x32_bf16(wfr, a[s], acc, 0, 0, 0);
            }
            const float4 bn = *(const float4*)(bias + nt * 16 + q * 4);
            const float bnv[4] = {bn.x, bn.y, bn.z, bn.w};
#pragma unroll
            for (int reg = 0; reg < 4; ++reg) {
                const float z  = acc[reg] + bnv[reg];
                const float hh = z / (1.f + __expf(-z));       // silu
                h[tt][reg] = hh;
                s_acc  += hh;
                ss_acc += hh * hh;
            }
        }

        // reduce across the 4 lanes holding token m (lanes m, m+16, m+32, m+48)
        s_acc  += __shfl_xor(s_acc,  16, 64);
        ss_acc += __shfl_xor(ss_acc, 16, 64);
        s_acc  += __shfl_xor(s_acc,  32, 64);
        ss_acc += __shfl_xor(ss_acc, 32, 64);
        if (q == 0) { ps[m][wave] = s_acc; pss[m][wave] = ss_acc; }
    }
    __syncthreads();

    {
        const int m = lane & 15;
        const int q = lane >> 4;

        const float4 p4  = *(const float4*)(&ps[m][0]);
        const float4 pq4 = *(const float4*)(&pss[m][0]);
        const float s_tot  = (p4.x  + p4.y)  + (p4.z  + p4.w);
        const float ss_tot = (pq4.x + pq4.y) + (pq4.z + pq4.w);
        const float mu   = s_tot * (1.f / D_);
        const float var  = ss_tot * (1.f / D_) - mu * mu;
        const float rsig = rsqrtf(var + LN_EPS);

        float* __restrict__ orow = out + ((size_t)b * NTOK_ + m) * D_;

        // recover h from the register file laid out in the first phase-2 scope:
        // (h, computed above, is still live — same scope trick via recompute of indices)
        // NOTE: h[][] was declared in the previous block; hoist stores here instead.
        (void)q; (void)orow;
    }

    // --- stores (kept in the same scope as h by restructuring) ---
    // The above split into two blocks would lose h; do the LN finish + stores in
    // one scope instead:
    // (The code below replaces the placeholder block logic.)
    {
    }
}

// ------- NOTE: the kernel above is superseded by this corrected definition -------
// (single-scope version so h[][] stays live across the barrier)
__global__ __launch_bounds__(256) void fused_tokenizer_kernel_v2(
    const int*   __restrict__ int_feats,
    const int*   __restrict__ missing_mask,
    const int*   __restrict__ group_idx,
    const float* __restrict__ emb_tables,
    const float* __restrict__ missing_emb,
    const unsigned short* __restrict__ Wb,
    const float* __restrict__ bias,
    const float* __restrict__ gamma,
    const float* __restrict__ beta,
    float*       __restrict__ out)
{
    __shared__ unsigned short xs[NTOK_][XSP];
    __shared__ float ps [NTOK_][4];
    __shared__ float pss[NTOK_][4];

    const int tid  = threadIdx.x;
    const int b    = blockIdx.x;
    const int lane = tid & 63;
    const int wave = tid >> 6;

    const int* __restrict__ feats_row = int_feats    + b * F_;
    const int* __restrict__ mask_row  = missing_mask + b * F_;

#pragma unroll
    for (int i = 0; i < 2; ++i) {
        const int c  = i * 256 + tid;
        const int n  = c >> 5;
        const int r4 = c & 31;
        const int t  = r4 >> 4;
        const int e  = (r4 & 15) * 4;
        const int4 fv = *(const int4*)(group_idx + n * G_);
        const int fs[4] = {fv.x, fv.y, fv.z, fv.w};
        float ax = 0.f, ay = 0.f, az = 0.f, aw = 0.f;
#pragma unroll
        for (int g = 0; g < G_; ++g) {
            const int f  = fs[g];
            const int id = feats_row[f];
            const float mk = (float)mask_row[f];
            const float4 v  = *(const float4*)(emb_tables + (((size_t)(t * F_ + f) * V_) + id) * E_ + e);
            const float4 mv = *(const float4*)(missing_emb + (size_t)(t * F_ + f) * E_ + e);
            ax += v.x + mk * mv.x;
            ay += v.y + mk * mv.y;
            az += v.z + mk * mv.z;
            aw += v.w + mk * mv.w;
        }
        union { unsigned int u[2]; } pk;
        pk.u[0] = (unsigned int)f2bf(0.25f * ax) | ((unsigned int)f2bf(0.25f * ay) << 16);
        pk.u[1] = (unsigned int)f2bf(0.25f * az) | ((unsigned int)f2bf(0.25f * aw) << 16);
        *(uint2*)(&xs[n][r4 * 4]) = make_uint2(pk.u[0], pk.u[1]);
    }
    __syncthreads();

    const int m = lane & 15;   // token (D col of MFMA result)
    const int q = lane >> 4;

    frag_ab a[4];
#pragma unroll
    for (int s = 0; s < 4; ++s)
        a[s] = *(const frag_ab*)(&xs[m][32 * s + 8 * q]);

    float h[4][4];
    float s_acc = 0.f, ss_acc = 0.f;

#pragma unroll
    for (int tt = 0; tt < 4; ++tt) {
        const int nt   = wave * 4 + tt;
        const int nrow = nt * 16 + m;
        const unsigned short* wp = Wb + (size_t)nrow * K_ + 8 * q;

        frag_cd acc = {0.f, 0.f, 0.f, 0.f};
#pragma unroll
        for (int s = 0; s < 4; ++s) {
            const frag_ab wfr = *(const frag_ab*)(wp + 32 * s);
            acc = __builtin_amdgcn_mfma_f32_16x16x32_bf16(wfr, a[s], acc, 0, 0, 0);
        }
        const float4 bn = *(const float4*)(bias + nt * 16 + q * 4);
        const float bnv[4] = {bn.x, bn.y, bn.z, bn.w};
#pragma unroll
        for (int reg = 0; reg < 4; ++reg) {
            const float z  = acc[reg] + bnv[reg];
            const float hh = z / (1.f + __expf(-z));
            h[tt][reg] = hh;
            s_acc  += hh;
            ss_acc += hh * hh;
        }
    }

    s_acc  += __shfl_xor(s_acc,  16, 64);
    ss_acc += __shfl_xor(ss_acc, 16, 64);
    s_acc  += __shfl_xor(s_acc,  32, 64);
    ss_acc += __shfl_xor(ss_acc, 32, 64);
    if (q == 0) { ps[m][wave] = s_acc; pss[m][wave] = ss_acc; }
    __syncthreads();

    const float4 p4  = *(const float4*)(&ps[m][0]);
    const float4 pq4 = *(const float4*)(&pss[m][0]);
    const float s_tot  = (p4.x  + p4.y)  + (p4.z  + p4.w);
    const float ss_tot = (pq4.x + pq4.y) + (pq4.z + pq4.w);
    const float mu   = s_tot * (1.f / D_);
    const float var  = ss_tot * (1.f / D_) - mu * mu;
    const float rsig = rsqrtf(var + LN_EPS);

    float* __restrict__ orow = out + ((size_t)b * NTOK_ + m) * D_;
#pragma unroll
    for (int tt = 0; tt < 4; ++tt) {
        const int nt  = wave * 4 + tt;
        const int col = nt * 16 + q * 4;
        const float4 gm = *(const float4*)(gamma + col);
        const float4 bt = *(const float4*)(beta  + col);
        float4 o;
        o.x = (h[tt][0] - mu) * rsig * gm.x + bt.x;
        o.y = (h[tt][1] - mu) * rsig * gm.y + bt.y;
        o.z = (h[tt][2] - mu) * rsig * gm.z + bt.z;
        o.w = (h[tt][3] - mu) * rsig * gm.w + bt.w;
        *(float4*)(orow + col) = o;
    }
}

extern "C" void kernel_launch(void* const* d_in, const int* in_sizes, int n_in,
                              void* d_out, int out_size, void* d_ws, size_t ws_size,
                              hipStream_t stream) {
    const int*   int_feats    = (const int*)  d_in[0];
    const int*   missing_mask = (const int*)  d_in[1];
    const int*   group_idx    = (const int*)  d_in[2];
    const float* emb_tables   = (const float*)d_in[3];
    const float* missing_emb  = (const float*)d_in[4];
    const float* W            = (const float*)d_in[5];
    const float* bias         = (const float*)d_in[6];
    const float* gamma        = (const float*)d_in[7];
    const float* beta         = (const float*)d_in[8];
    float* out = (float*)d_out;

    unsigned short* Wb = (unsigned short*)d_ws;   // 64 KB bf16 copy of W

    convert_w_kernel<<<(D_ * K_ / 2 + 255) / 256, 256, 0, stream>>>(W, (unsigned int*)Wb);
    fused_tokenizer_kernel_v2<<<B_, 256, 0, stream>>>(
        int_feats, missing_mask, group_idx, emb_tables, missing_emb,
        Wb, bias, gamma, beta, out);
}

// Round 2
// 248.918 us; speedup vs baseline: 1.0318x; 1.0318x over previous
//
#include <hip/hip_runtime.h>
#include <math.h>

// Problem constants (match reference)
#define B_    8192
#define F_    64
#define V_    1000
#define E_    64
#define T_    2
#define NTOK_ 16
#define G_    4
#define D_    256
#define K_    128   // T*E
#define LN_EPS 1e-5f

#define XSP   136   // xs row stride in bf16 elements (128 + 8 pad)
#define HSP   260   // hs row stride in floats (256 + 4: float4-aligned rows)

typedef __attribute__((ext_vector_type(8))) short  frag_ab;  // 8 bf16 = 4 VGPRs
typedef __attribute__((ext_vector_type(4))) float  frag_cd;  // 4 fp32 acc

static __device__ __forceinline__ unsigned short f2bf(float f) {
    // round-to-nearest-even fp32 -> bf16 (values are finite here)
    unsigned int u = __float_as_uint(f);
    u += 0x7FFFu + ((u >> 16) & 1u);
    return (unsigned short)(u >> 16);
}

// ---- prologue: W fp32 (D,K) -> bf16 in workspace (row-major, same layout) ----
__global__ __launch_bounds__(256) void convert_w_kernel(const float* __restrict__ W,
                                                        unsigned int* __restrict__ Wb_packed) {
    const int i = blockIdx.x * 256 + threadIdx.x;   // one uint = 2 bf16
    if (i < (D_ * K_) / 2) {
        const float2 v = *(const float2*)(W + (size_t)i * 2);
        Wb_packed[i] = (unsigned int)f2bf(v.x) | ((unsigned int)f2bf(v.y) << 16);
    }
}

// One block per batch row b. 256 threads = 4 waves.
// Phase 1 (r0-proven): staged indices, float4 gather + mean-pool -> xs bf16 LDS.
// Phase 2 (v2-proven math): MFMA 16x16x32 bf16 with SWAPPED operands
//          (A = W rows, B = x) so D col(lane&15) = token, rows = output cols
//          16*nt + 4q + reg. All 16 accs of a lane belong to ONE token ->
//          LN stats are lane-local adds + shfl_xor(16,32) + 4-entry LDS combine.
//          Normalize in registers, transpose through LDS (hs aliases xs).
// Phase 3 (r0-proven): coalesced 1KB-contiguous float4 stores per token.
__global__ __launch_bounds__(256) void fused_tokenizer_kernel(
    const int*   __restrict__ int_feats,     // (B, F)
    const int*   __restrict__ missing_mask,  // (B, F)
    const int*   __restrict__ group_idx,     // (NTOK, G)
    const float* __restrict__ emb_tables,    // (T, F, V, E)
    const float* __restrict__ missing_emb,   // (T, F, E)
    const unsigned short* __restrict__ Wb,   // (D, K) bf16
    const float* __restrict__ bias,          // (D,)
    const float* __restrict__ gamma,         // (D,)
    const float* __restrict__ beta,          // (D,)
    float*       __restrict__ out)           // (B, NTOK, D)
{
    // hs (16x260 fp32 = 16640 B) aliases xs (16x136 bf16 = 4352 B): last xs
    // read (frag loads) and first hs write are separated by the ps/pss barrier.
    __shared__ __align__(16) char smem[NTOK_ * HSP * 4];
    unsigned short (*xs)[XSP] = (unsigned short (*)[XSP])smem;
    float          (*hs)[HSP] = (float (*)[HSP])smem;

    __shared__ int   sid[F_];
    __shared__ int   smask[F_];
    __shared__ int   sg[NTOK_ * G_];
    __shared__ float ps [NTOK_][4];   // per-wave partial sum   (token, wave)
    __shared__ float pss[NTOK_][4];   // per-wave partial sumsq

    const int tid  = threadIdx.x;
    const int b    = blockIdx.x;
    const int lane = tid & 63;
    const int wave = tid >> 6;

    if (tid < F_) {
        sid[tid]   = int_feats[b * F_ + tid];
        smask[tid] = missing_mask[b * F_ + tid];
        sg[tid]    = group_idx[tid];   // NTOK*G == F == 64
    }
    __syncthreads();

    // ---- Phase 1: gather + mean-pool (float4 granularity) ----
    // chunk c in [0,512): n = c>>5 (token), r4 = c&31, t = r4>>4, e = (r4&15)*4
    // 16 consecutive lanes cover one 256B embedding row -> coalesced dwordx4.
#pragma unroll
    for (int i = 0; i < 2; ++i) {
        const int c  = i * 256 + tid;
        const int n  = c >> 5;
        const int r4 = c & 31;
        const int t  = r4 >> 4;
        const int e  = (r4 & 15) * 4;
        float ax = 0.f, ay = 0.f, az = 0.f, aw = 0.f;
#pragma unroll
        for (int g = 0; g < G_; ++g) {
            const int f  = sg[n * G_ + g];
            const int id = sid[f];
            const float4 v = *(const float4*)(emb_tables + (((size_t)(t * F_ + f) * V_) + id) * E_ + e);
            float vx = v.x, vy = v.y, vz = v.z, vw = v.w;
            if (smask[f]) {
                const float4 mv = *(const float4*)(missing_emb + (size_t)(t * F_ + f) * E_ + e);
                vx += mv.x; vy += mv.y; vz += mv.z; vw += mv.w;
            }
            ax += vx; ay += vy; az += vz; aw += vw;
        }
        union { unsigned int u[2]; } pk;
        pk.u[0] = (unsigned int)f2bf(0.25f * ax) | ((unsigned int)f2bf(0.25f * ay) << 16);
        pk.u[1] = (unsigned int)f2bf(0.25f * az) | ((unsigned int)f2bf(0.25f * aw) << 16);
        *(uint2*)(&xs[n][r4 * 4]) = make_uint2(pk.u[0], pk.u[1]);
    }
    __syncthreads();

    // ---- Phase 2: swapped-operand MFMA + silu + register LN ----
    const int m = lane & 15;   // token index (D col of MFMA result)
    const int q = lane >> 4;   // quadrant

    // x fragment: lane holds x[token=m][k = 8q + j + 32s]
    frag_ab a[4];
#pragma unroll
    for (int s = 0; s < 4; ++s)
        a[s] = *(const frag_ab*)(&xs[m][32 * s + 8 * q]);

    float h[4][4];             // h[tt][reg]: silu outputs, cols 16*(4*wave+tt)+4q+reg, token m
    float s_acc = 0.f, ss_acc = 0.f;

#pragma unroll
    for (int tt = 0; tt < 4; ++tt) {
        const int nt   = wave * 4 + tt;        // n-tile
        const int nrow = nt * 16 + m;          // W row this lane supplies (A operand M dim)
        const unsigned short* wp = Wb + (size_t)nrow * K_ + 8 * q;

        frag_cd acc = {0.f, 0.f, 0.f, 0.f};
#pragma unroll
        for (int s = 0; s < 4; ++s) {
            const frag_ab wfr = *(const frag_ab*)(wp + 32 * s);
            // A = W (M = output col), B = x (N = token)
            acc = __builtin_amdgcn_mfma_f32_16x16x32_bf16(wfr, a[s], acc, 0, 0, 0);
        }
        const float4 bn = *(const float4*)(bias + nt * 16 + q * 4);
        const float bnv[4] = {bn.x, bn.y, bn.z, bn.w};
#pragma unroll
        for (int reg = 0; reg < 4; ++reg) {
            const float z  = acc[reg] + bnv[reg];
            const float hh = z / (1.f + __expf(-z));       // silu
            h[tt][reg] = hh;
            s_acc  += hh;
            ss_acc += hh * hh;
        }
    }

    // reduce across the 4 lanes holding token m (lanes m, m+16, m+32, m+48)
    s_acc  += __shfl_xor(s_acc,  16, 64);
    ss_acc += __shfl_xor(ss_acc, 16, 64);
    s_acc  += __shfl_xor(s_acc,  32, 64);
    ss_acc += __shfl_xor(ss_acc, 32, 64);
    if (q == 0) { ps[m][wave] = s_acc; pss[m][wave] = ss_acc; }
    __syncthreads();   // also fences last xs read before hs writes (aliased)

    const float4 p4  = *(const float4*)(&ps[m][0]);
    const float4 pq4 = *(const float4*)(&pss[m][0]);
    const float s_tot  = (p4.x  + p4.y)  + (p4.z  + p4.w);
    const float ss_tot = (pq4.x + pq4.y) + (pq4.z + pq4.w);
    const float mu   = s_tot * (1.f / D_);
    const float var  = ss_tot * (1.f / D_) - mu * mu;
    const float rsig = rsqrtf(var + LN_EPS);

    // normalize in registers, transpose through LDS
#pragma unroll
    for (int tt = 0; tt < 4; ++tt) {
        const int col = (wave * 4 + tt) * 16 + q * 4;
        const float4 gm = *(const float4*)(gamma + col);
        const float4 bt = *(const float4*)(beta  + col);
        float4 o;
        o.x = (h[tt][0] - mu) * rsig * gm.x + bt.x;
        o.y = (h[tt][1] - mu) * rsig * gm.y + bt.y;
        o.z = (h[tt][2] - mu) * rsig * gm.z + bt.z;
        o.w = (h[tt][3] - mu) * rsig * gm.w + bt.w;
        *(float4*)(&hs[m][col]) = o;
    }
    __syncthreads();

    // ---- Phase 3: coalesced copy-out; wave w stores tokens 4w..4w+3 ----
#pragma unroll
    for (int qq = 0; qq < 4; ++qq) {
        const int n = wave * 4 + qq;
        const float4 v = *(const float4*)(&hs[n][lane * 4]);
        *(float4*)(out + ((size_t)b * NTOK_ + n) * D_ + lane * 4) = v;
    }
}

extern "C" void kernel_launch(void* const* d_in, const int* in_sizes, int n_in,
                              void* d_out, int out_size, void* d_ws, size_t ws_size,
                              hipStream_t stream) {
    const int*   int_feats    = (const int*)  d_in[0];
    const int*   missing_mask = (const int*)  d_in[1];
    const int*   group_idx    = (const int*)  d_in[2];
    const float* emb_tables   = (const float*)d_in[3];
    const float* missing_emb  = (const float*)d_in[4];
    const float* W            = (const float*)d_in[5];
    const float* bias         = (const float*)d_in[6];
    const float* gamma        = (const float*)d_in[7];
    const float* beta         = (const float*)d_in[8];
    float* out = (float*)d_out;

    unsigned short* Wb = (unsigned short*)d_ws;   // 64 KB bf16 copy of W

    convert_w_kernel<<<(D_ * K_ / 2 + 255) / 256, 256, 0, stream>>>(W, (unsigned int*)Wb);
    fused_tokenizer_kernel<<<B_, 256, 0, stream>>>(
        int_feats, missing_mask, group_idx, emb_tables, missing_emb,
        Wb, bias, gamma, beta, out);
}

// Round 4
// 248.318 us; speedup vs baseline: 1.0343x; 1.0024x over previous
//
#include <hip/hip_runtime.h>
#include <math.h>

// Problem constants (match reference)
#define B_    8192
#define F_    64
#define V_    1000
#define E_    64
#define T_    2
#define NTOK_ 16
#define G_    4
#define D_    256
#define K_    128   // T*E
#define LN_EPS 1e-5f

#define XSP   136   // xs row stride in bf16 elements (128 + 8 pad)
#define HSP   260   // hs row stride in floats (256 + 4: float4-aligned rows)

typedef __attribute__((ext_vector_type(8))) short  frag_ab;  // 8 bf16 = 4 VGPRs
typedef __attribute__((ext_vector_type(4))) float  frag_cd;  // 4 fp32 acc
typedef __attribute__((ext_vector_type(4))) float  f32x4;    // native vec4 (NT-store legal)

static __device__ __forceinline__ unsigned short f2bf(float f) {
    // round-to-nearest-even fp32 -> bf16 (values are finite here)
    unsigned int u = __float_as_uint(f);
    u += 0x7FFFu + ((u >> 16) & 1u);
    return (unsigned short)(u >> 16);
}

// ---- prologue: W fp32 (D,K) -> bf16 in workspace (row-major, same layout) ----
__global__ __launch_bounds__(256) void convert_w_kernel(const float* __restrict__ W,
                                                        unsigned int* __restrict__ Wb_packed) {
    const int i = blockIdx.x * 256 + threadIdx.x;   // one uint = 2 bf16
    if (i < (D_ * K_) / 2) {
        const float2 v = *(const float2*)(W + (size_t)i * 2);
        const unsigned int p = (unsigned int)f2bf(v.x) | ((unsigned int)f2bf(v.y) << 16);
        __builtin_nontemporal_store(p, Wb_packed + i);
    }
}

// One block per batch row b. 256 threads = 4 waves.
// Phase 1: staged indices, float4 gather + mean-pool -> xs bf16 LDS.
//          Gather reads rely on L3 retaining the 33MB emb_tables — which is
//          why ALL output stores are non-temporal (streaming writes were
//          evicting the table: FETCH_SIZE 122MB vs 38MB compulsory).
// Phase 2: MFMA 16x16x32 bf16, SWAPPED operands (A=W rows, B=x): D col = token,
//          rows = output cols 16*nt+4q+reg. LN stats = lane adds + 2 shfl_xor +
//          4-entry LDS combine. Normalize in registers, transpose via hs LDS
//          (hs aliases xs; ps/pss barrier fences the overlap).
// Phase 3: coalesced 1KB-contiguous float4 NT stores per token.
__global__ __launch_bounds__(256) void fused_tokenizer_kernel(
    const int*   __restrict__ int_feats,     // (B, F)
    const int*   __restrict__ missing_mask,  // (B, F)
    const int*   __restrict__ group_idx,     // (NTOK, G)
    const float* __restrict__ emb_tables,    // (T, F, V, E)
    const float* __restrict__ missing_emb,   // (T, F, E)
    const unsigned short* __restrict__ Wb,   // (D, K) bf16
    const float* __restrict__ bias,          // (D,)
    const float* __restrict__ gamma,         // (D,)
    const float* __restrict__ beta,          // (D,)
    float*       __restrict__ out)           // (B, NTOK, D)
{
    __shared__ __align__(16) char smem[NTOK_ * HSP * 4];
    unsigned short (*xs)[XSP] = (unsigned short (*)[XSP])smem;
    float          (*hs)[HSP] = (float (*)[HSP])smem;

    __shared__ int   sid[F_];
    __shared__ int   smask[F_];
    __shared__ int   sg[NTOK_ * G_];
    __shared__ float ps [NTOK_][4];   // per-wave partial sum   (token, wave)
    __shared__ float pss[NTOK_][4];   // per-wave partial sumsq

    const int tid  = threadIdx.x;
    const int b    = blockIdx.x;
    const int lane = tid & 63;
    const int wave = tid >> 6;

    if (tid < F_) {
        sid[tid]   = int_feats[b * F_ + tid];
        smask[tid] = missing_mask[b * F_ + tid];
        sg[tid]    = group_idx[tid];   // NTOK*G == F == 64
    }
    __syncthreads();

    // ---- Phase 1: gather + mean-pool (float4 granularity) ----
    // chunk c in [0,512): n = c>>5 (token), r4 = c&31, t = r4>>4, e = (r4&15)*4
    // 16 consecutive lanes cover one 256B embedding row -> coalesced dwordx4.
#pragma unroll
    for (int i = 0; i < 2; ++i) {
        const int c  = i * 256 + tid;
        const int n  = c >> 5;
        const int r4 = c & 31;
        const int t  = r4 >> 4;
        const int e  = (r4 & 15) * 4;
        float ax = 0.f, ay = 0.f, az = 0.f, aw = 0.f;
#pragma unroll
        for (int g = 0; g < G_; ++g) {
            const int f  = sg[n * G_ + g];
            const int id = sid[f];
            const float4 v = *(const float4*)(emb_tables + (((size_t)(t * F_ + f) * V_) + id) * E_ + e);
            float vx = v.x, vy = v.y, vz = v.z, vw = v.w;
            if (smask[f]) {
                const float4 mv = *(const float4*)(missing_emb + (size_t)(t * F_ + f) * E_ + e);
                vx += mv.x; vy += mv.y; vz += mv.z; vw += mv.w;
            }
            ax += vx; ay += vy; az += vz; aw += vw;
        }
        union { unsigned int u[2]; } pk;
        pk.u[0] = (unsigned int)f2bf(0.25f * ax) | ((unsigned int)f2bf(0.25f * ay) << 16);
        pk.u[1] = (unsigned int)f2bf(0.25f * az) | ((unsigned int)f2bf(0.25f * aw) << 16);
        *(uint2*)(&xs[n][r4 * 4]) = make_uint2(pk.u[0], pk.u[1]);
    }
    __syncthreads();

    // ---- Phase 2: swapped-operand MFMA + silu + register LN ----
    const int m = lane & 15;   // token index (D col of MFMA result)
    const int q = lane >> 4;   // quadrant

    // x fragment: lane holds x[token=m][k = 8q + j + 32s]
    frag_ab a[4];
#pragma unroll
    for (int s = 0; s < 4; ++s)
        a[s] = *(const frag_ab*)(&xs[m][32 * s + 8 * q]);

    float h[4][4];             // h[tt][reg]: silu outputs, cols 16*(4*wave+tt)+4q+reg, token m
    float s_acc = 0.f, ss_acc = 0.f;

#pragma unroll
    for (int tt = 0; tt < 4; ++tt) {
        const int nt   = wave * 4 + tt;        // n-tile
        const int nrow = nt * 16 + m;          // W row this lane supplies (A operand M dim)
        const unsigned short* wp = Wb + (size_t)nrow * K_ + 8 * q;

        frag_cd acc = {0.f, 0.f, 0.f, 0.f};
#pragma unroll
        for (int s = 0; s < 4; ++s) {
            const frag_ab wfr = *(const frag_ab*)(wp + 32 * s);
            // A = W (M = output col), B = x (N = token)
            acc = __builtin_amdgcn_mfma_f32_16x16x32_bf16(wfr, a[s], acc, 0, 0, 0);
        }
        const float4 bn = *(const float4*)(bias + nt * 16 + q * 4);
        const float bnv[4] = {bn.x, bn.y, bn.z, bn.w};
#pragma unroll
        for (int reg = 0; reg < 4; ++reg) {
            const float z  = acc[reg] + bnv[reg];
            const float hh = z / (1.f + __expf(-z));       // silu
            h[tt][reg] = hh;
            s_acc  += hh;
            ss_acc += hh * hh;
        }
    }

    // reduce across the 4 lanes holding token m (lanes m, m+16, m+32, m+48)
    s_acc  += __shfl_xor(s_acc,  16, 64);
    ss_acc += __shfl_xor(ss_acc, 16, 64);
    s_acc  += __shfl_xor(s_acc,  32, 64);
    ss_acc += __shfl_xor(ss_acc, 32, 64);
    if (q == 0) { ps[m][wave] = s_acc; pss[m][wave] = ss_acc; }
    __syncthreads();   // also fences last xs read before hs writes (aliased)

    const float4 p4  = *(const float4*)(&ps[m][0]);
    const float4 pq4 = *(const float4*)(&pss[m][0]);
    const float s_tot  = (p4.x  + p4.y)  + (p4.z  + p4.w);
    const float ss_tot = (pq4.x + pq4.y) + (pq4.z + pq4.w);
    const float mu   = s_tot * (1.f / D_);
    const float var  = ss_tot * (1.f / D_) - mu * mu;
    const float rsig = rsqrtf(var + LN_EPS);

    // normalize in registers, transpose through LDS
#pragma unroll
    for (int tt = 0; tt < 4; ++tt) {
        const int col = (wave * 4 + tt) * 16 + q * 4;
        const float4 gm = *(const float4*)(gamma + col);
        const float4 bt = *(const float4*)(beta  + col);
        float4 o;
        o.x = (h[tt][0] - mu) * rsig * gm.x + bt.x;
        o.y = (h[tt][1] - mu) * rsig * gm.y + bt.y;
        o.z = (h[tt][2] - mu) * rsig * gm.z + bt.z;
        o.w = (h[tt][3] - mu) * rsig * gm.w + bt.w;
        *(float4*)(&hs[m][col]) = o;
    }
    __syncthreads();

    // ---- Phase 3: coalesced copy-out, NON-TEMPORAL (don't evict the table) ----
#pragma unroll
    for (int qq = 0; qq < 4; ++qq) {
        const int n = wave * 4 + qq;
        const f32x4 v = *(const f32x4*)(&hs[n][lane * 4]);
        __builtin_nontemporal_store(v, (f32x4*)(out + ((size_t)b * NTOK_ + n) * D_ + lane * 4));
    }
}

extern "C" void kernel_launch(void* const* d_in, const int* in_sizes, int n_in,
                              void* d_out, int out_size, void* d_ws, size_t ws_size,
                              hipStream_t stream) {
    const int*   int_feats    = (const int*)  d_in[0];
    const int*   missing_mask = (const int*)  d_in[1];
    const int*   group_idx    = (const int*)  d_in[2];
    const float* emb_tables   = (const float*)d_in[3];
    const float* missing_emb  = (const float*)d_in[4];
    const float* W            = (const float*)d_in[5];
    const float* bias         = (const float*)d_in[6];
    const float* gamma        = (const float*)d_in[7];
    const float* beta         = (const float*)d_in[8];
    float* out = (float*)d_out;

    unsigned short* Wb = (unsigned short*)d_ws;   // 64 KB bf16 copy of W

    convert_w_kernel<<<(D_ * K_ / 2 + 255) / 256, 256, 0, stream>>>(W, (unsigned int*)Wb);
    fused_tokenizer_kernel<<<B_, 256, 0, stream>>>(
        int_feats, missing_mask, group_idx, emb_tables, missing_emb,
        Wb, bias, gamma, beta, out);
}